// Round 13
// baseline (325.687 us; speedup 1.0000x reference)
//
#include <hip/hip_runtime.h>
#include <hip/hip_bf16.h>
#include <stdint.h>

#define ALPHA 1.0f

typedef __attribute__((ext_vector_type(8))) short bf16x8;
typedef __attribute__((ext_vector_type(4))) float f32x4;
typedef unsigned short ushort_t;

__device__ __forceinline__ unsigned short f32_to_bf16_rne(float f) {
    union { float f; unsigned int u; } v; v.f = f;
    unsigned int u = v.u;
    unsigned int r = u + 0x7FFFu + ((u >> 16) & 1u);
    return (unsigned short)(r >> 16);
}

__device__ __forceinline__ unsigned int cvt_pk_bf16(float lo, float hi) {
    unsigned int r;
    asm("v_cvt_pk_bf16_f32 %0, %1, %2" : "=v"(r) : "v"(lo), "v"(hi));
    return r;
}

__device__ __forceinline__ void async_copy16(const void* g, void* l) {
    __builtin_amdgcn_global_load_lds(
        (const __attribute__((address_space(1))) void*)g,
        (__attribute__((address_space(3))) void*)l, 16, 0, 0);
}

// ---------------------------------------------------------------------------
// Fused W_eff: weff[o][i] = W[o][i] + ALPHA * sum_r fac[o][r] * t1[r][i]
template <bool BF16OUT>
__global__ __launch_bounds__(256)
void weff_fused_kernel(const float* __restrict__ W,
                       const float* __restrict__ lora_down,
                       const float* __restrict__ lora_up,
                       const float* __restrict__ down_aux,
                       const float* __restrict__ up_aux,
                       void* __restrict__ weff) {
    int o = blockIdx.x;
    int i0 = threadIdx.x * 4;

    float fac[4] = {0.f, 0.f, 0.f, 0.f};
    for (int u = 0; u < 50; ++u) {
        float ua = up_aux[o * 50 + u] * ALPHA;
#pragma unroll
        for (int r = 0; r < 4; ++r) fac[r] += ua * lora_up[u * 4 + r];
    }

    float4 t1[4];
#pragma unroll
    for (int r = 0; r < 4; ++r) t1[r] = make_float4(0.f, 0.f, 0.f, 0.f);
    for (int d = 0; d < 100; ++d) {
        float4 da = *(const float4*)(down_aux + d * 1024 + i0);
#pragma unroll
        for (int r = 0; r < 4; ++r) {
            float ld = lora_down[r * 100 + d];
            t1[r].x += ld * da.x; t1[r].y += ld * da.y;
            t1[r].z += ld * da.z; t1[r].w += ld * da.w;
        }
    }

    float4 acc = *(const float4*)(W + (long)o * 1024 + i0);
#pragma unroll
    for (int r = 0; r < 4; ++r) {
        acc.x += fac[r] * t1[r].x; acc.y += fac[r] * t1[r].y;
        acc.z += fac[r] * t1[r].z; acc.w += fac[r] * t1[r].w;
    }

    if (BF16OUT) {
        ushort4 rr;
        rr.x = f32_to_bf16_rne(acc.x); rr.y = f32_to_bf16_rne(acc.y);
        rr.z = f32_to_bf16_rne(acc.z); rr.w = f32_to_bf16_rne(acc.w);
        *(ushort4*)((ushort_t*)weff + (long)o * 1024 + i0) = rr;
    } else {
        *(float4*)((float*)weff + (long)o * 1024 + i0) = acc;
    }
}

// ---------------------------------------------------------------------------
// Fused GEMM: C = cvt_bf16(A_f32[M][K]) * Bt_bf16[N][K]^T + bias
// 128x128 tile, BK=32, 4 waves (2x2), per-wave 64x64 = acc[4][4] f32x4.
// Double-buffered A (reg-staged cvt) + B (glds), 32 KB LDS -> 3 blocks/CU
// (R1's TLP regime) + counted-vmcnt raw-barrier sync (R7's mechanism).
// NO vmcnt(0) drain anywhere in the main loop.
//
// A staging (R12 bug fixed): thread -> row ar = tid>>1, half ah = tid&1;
//   loads 16 f32 (4x float4) at col ah*16; cvt_pk -> two 16B bf16 chunks
//   (logical chunks 2ah, 2ah+1) written at XOR-swizzled positions.
//   Coverage: 256 thr x 16 f32 = 4096 = 128 x 32 tile. Exact.
//
// Per iter j (buf c = j&1, o = c^1), VMEM queue audit:
//   1. frag reads Ab[c], Bb[c]           (8 ds_read_b128)
//   2. stageB(j+1) -> Bb[o]              queue: [A(j+1) 4, B(j+1) 2]
//   3. 16 MFMA
//   4. writeA(o): compiler waits vA -> vmcnt(2); retires A(j+1), keeps B
//   5. loadA(j+2) -> vA                  queue: [B(j+1) 2, A(j+2) 4]
//   6. gate: vmcnt(4) lgkmcnt(0) + s_barrier  (retires B(j+1) only)
#define BM 128
#define BN 128
#define BK 32

__global__ __launch_bounds__(256, 3)
void gemm_fused_kernel(const float* __restrict__ A,
                       const ushort_t* __restrict__ Bt,
                       const float* __restrict__ bias,
                       float* __restrict__ C, int M, int N, int K) {
    __shared__ __align__(16) ushort_t Ab[2][BM * BK];  // 2 x 8 KB
    __shared__ __align__(16) ushort_t Bb[2][BN * BK];  // 2 x 8 KB

    int nTilesN = N / BN;  // 8
    int nwg = gridDim.x;
    int bid = blockIdx.x;
    int swz = bid;
    if ((nwg & 7) == 0) {   // grid = 4096 -> bijective XCD swizzle
        int cpx = nwg >> 3;
        swz = (bid & 7) * cpx + (bid >> 3);
    }
    int tm = swz / nTilesN;   // 8 consecutive swz on one XCD share an A panel
    int tn = swz % nTilesN;
    const long rowA0 = (long)tm * BM;
    const long colB0 = (long)tn * BN;

    int tid = threadIdx.x;
    int lane = tid & 63;
    int wave = tid >> 6;       // 0..3
    int wr = wave >> 1;        // 0..1
    int wc = wave & 1;         // 0..1

    // ---- A staging map: row ar (0..127), half ah (16 f32 each) ----
    int ar = tid >> 1;
    int ah = tid & 1;
    int keyA = (ar & 3) ^ ((ar >> 2) & 3);
    int sA0 = (2 * ah) ^ keyA;       // swizzled 16B-chunk positions
    int sA1 = (2 * ah + 1) ^ keyA;

    // ---- B staging map (glds, pre-swizzled source): 2 sweeps x 16B ----
    int brow[2], bcol[2];
#pragma unroll
    for (int q = 0; q < 2; ++q) {
        int pc = q * 256 + tid;
        brow[q] = pc >> 2;
        int kb = (brow[q] & 3) ^ ((brow[q] >> 2) & 3);
        bcol[q] = (pc & 3) ^ kb;
    }

    // ---- fragment map ----
    int fr = lane & 15;
    int h4 = lane >> 4;                       // 0..3 (16B chunk index)
    int keyF = (fr & 3) ^ ((fr >> 2) & 3);    // == key(row): offsets mult of 16
    int fchunk = (h4 ^ keyF) * 8;             // element offset in 32-elem row
    int aoff = (wr * 64 + fr) * BK;
    int boff = (wc * 64 + fr) * BK;

    f32x4 acc[4][4];
#pragma unroll
    for (int m = 0; m < 4; ++m)
#pragma unroll
        for (int n = 0; n < 4; ++n) acc[m][n] = (f32x4)(0.0f);

    const int nIter = K / BK;   // 32

    float4 vA0, vA1, vA2, vA3;   // 16 regs: next A tile's 16 f32 per thread

    auto loadA = [&](int kt) {
        const float* p = A + (rowA0 + ar) * (long)K + kt * BK + ah * 16;
        vA0 = ((const float4*)p)[0];
        vA1 = ((const float4*)p)[1];
        vA2 = ((const float4*)p)[2];
        vA3 = ((const float4*)p)[3];
    };
    auto writeA = [&](int buf) {
        uint4 w1, w2;
        w1.x = cvt_pk_bf16(vA0.x, vA0.y);
        w1.y = cvt_pk_bf16(vA0.z, vA0.w);
        w1.z = cvt_pk_bf16(vA1.x, vA1.y);
        w1.w = cvt_pk_bf16(vA1.z, vA1.w);
        w2.x = cvt_pk_bf16(vA2.x, vA2.y);
        w2.y = cvt_pk_bf16(vA2.z, vA2.w);
        w2.z = cvt_pk_bf16(vA3.x, vA3.y);
        w2.w = cvt_pk_bf16(vA3.z, vA3.w);
        *(uint4*)&Ab[buf][ar * BK + sA0 * 8] = w1;
        *(uint4*)&Ab[buf][ar * BK + sA1 * 8] = w2;
    };
    auto stageB = [&](int kt, int buf) {
#pragma unroll
        for (int q = 0; q < 2; ++q) {
            const ushort_t* src =
                Bt + (colB0 + brow[q]) * (long)K + kt * BK + bcol[q] * 8;
            ushort_t* dst = &Bb[buf][(q * 256 + wave * 64) * 8];
            async_copy16(src, dst);
        }
    };

    // ---------------- prologue ----------------
    loadA(0);                 // queue: [A0 4]
    stageB(0, 0);             // queue: [A0 4, B0 2]
    writeA(0);                // compiler waits A0 -> vmcnt(2) (one-time HBM)
    loadA(1);                 // queue: [B0 2, A1 4]
    asm volatile("s_waitcnt vmcnt(4) lgkmcnt(0)" ::: "memory");  // B0 landed
    __builtin_amdgcn_s_barrier();

#pragma unroll 1
    for (int j = 0; j < nIter; ++j) {
        int c = j & 1, o = c ^ 1;
        bool s1 = (j + 1 < nIter);
        bool s2 = (j + 2 < nIter);

        // 1. fragment reads (buf c)
        bf16x8 a[4], b[4];
#pragma unroll
        for (int m = 0; m < 4; ++m)
            a[m] = *(const bf16x8*)&Ab[c][aoff + m * 16 * BK + fchunk];
#pragma unroll
        for (int n = 0; n < 4; ++n)
            b[n] = *(const bf16x8*)&Bb[c][boff + n * 16 * BK + fchunk];

        // 2. stage B(j+1) -> Bb[o]  (lands under MFMA + gate)
        if (s1) stageB(j + 1, o);

        // 3. MFMA
#pragma unroll
        for (int m = 0; m < 4; ++m)
#pragma unroll
            for (int n = 0; n < 4; ++n)
                acc[m][n] = __builtin_amdgcn_mfma_f32_16x16x32_bf16(
                    a[m], b[n], acc[m][n], 0, 0, 0);

        // 4. cvt+write A(j+1) -> Ab[o]  (vA aged ~1 iter; waits vmcnt(2))
        if (s1) writeA(o);

        // 5. issue A(j+2) f32 loads
        if (s2) loadA(j + 2);

        // 6. gate: ds_writes drained; B(j+1) retired; A(j+2) stays in flight
        if (s2) {
            asm volatile("s_waitcnt vmcnt(4) lgkmcnt(0)" ::: "memory");
        } else if (s1) {
            asm volatile("s_waitcnt vmcnt(0) lgkmcnt(0)" ::: "memory");
        } else {
            asm volatile("s_waitcnt lgkmcnt(0)" ::: "memory");
        }
        __builtin_amdgcn_s_barrier();
    }

    // ---- epilogue: C = acc + bias ----
    int ccol = lane & 15;
    int crow = (lane >> 4) * 4;
#pragma unroll
    for (int m = 0; m < 4; ++m) {
        long grow = rowA0 + wr * 64 + m * 16 + crow;
#pragma unroll
        for (int n = 0; n < 4; ++n) {
            long gcol = colB0 + wc * 64 + n * 16 + ccol;
            float bb = bias[gcol];
#pragma unroll
            for (int r = 0; r < 4; ++r) {
                C[(grow + r) * N + gcol] = acc[m][n][r] + bb;
            }
        }
    }
}

// ---------------------------------------------------------------------------
// Fallback: plain f32 tiled GEMM (used only if ws too small for bf16 path)
__global__ __launch_bounds__(256)
void gemm_f32_fallback(const float* __restrict__ A, const float* __restrict__ Bt,
                       const float* __restrict__ bias, float* __restrict__ C,
                       int M, int N, int K) {
    __shared__ float As[64][17];
    __shared__ float Bs[64][17];
    int tilesN = N / 64;
    int tm = blockIdx.x / tilesN;
    int tn = blockIdx.x % tilesN;
    int tid = threadIdx.x;
    int tr = tid / 16, tc = tid % 16;
    float acc[4][4] = {};
    for (int k0 = 0; k0 < K; k0 += 16) {
        for (int t = tid; t < 64 * 16; t += 256) {
            int r = t / 16, c = t % 16;
            As[r][c] = A[((long)tm * 64 + r) * K + k0 + c];
            Bs[r][c] = Bt[((long)tn * 64 + r) * K + k0 + c];
        }
        __syncthreads();
#pragma unroll
        for (int kk = 0; kk < 16; ++kk) {
            float av[4], bv[4];
#pragma unroll
            for (int i = 0; i < 4; ++i) av[i] = As[tr * 4 + i][kk];
#pragma unroll
            for (int j = 0; j < 4; ++j) bv[j] = Bs[tc * 4 + j][kk];
#pragma unroll
            for (int i = 0; i < 4; ++i)
#pragma unroll
                for (int j = 0; j < 4; ++j) acc[i][j] += av[i] * bv[j];
        }
        __syncthreads();
    }
#pragma unroll
    for (int i = 0; i < 4; ++i) {
        long row = (long)tm * 64 + tr * 4 + i;
#pragma unroll
        for (int j = 0; j < 4; ++j) {
            long col = (long)tn * 64 + tc * 4 + j;
            C[row * N + col] = acc[i][j] + bias[col];
        }
    }
}

// ---------------------------------------------------------------------------
extern "C" void kernel_launch(void* const* d_in, const int* in_sizes, int n_in,
                              void* d_out, int out_size, void* d_ws, size_t ws_size,
                              hipStream_t stream) {
    const float* hs        = (const float*)d_in[0];
    const float* W         = (const float*)d_in[1];
    const float* b         = (const float*)d_in[2];
    const float* lora_down = (const float*)d_in[3];
    const float* lora_up   = (const float*)d_in[4];
    const float* down_aux  = (const float*)d_in[5];
    const float* up_aux    = (const float*)d_in[6];
    float* out = (float*)d_out;

    const int K = 1024;   // IN
    const int N = 1024;   // OUT
    const int M = in_sizes[0] / K;  // B*S = 65536

    char* ws = (char*)d_ws;
    const size_t NEED_FAST = 2 * 1024 * 1024;   // weff bf16 only

    if (ws_size >= NEED_FAST && (M % BM) == 0) {
        ushort_t* weff = (ushort_t*)ws;
        weff_fused_kernel<true><<<N, 256, 0, stream>>>(W, lora_down, lora_up,
                                                       down_aux, up_aux, weff);
        int grid = (M / BM) * (N / BN);   // 4096
        gemm_fused_kernel<<<grid, 256, 0, stream>>>(hs, weff, b, out, M, N, K);
    } else {
        float* weff = (float*)ws;  // 4MB
        weff_fused_kernel<false><<<N, 256, 0, stream>>>(W, lora_down, lora_up,
                                                        down_aux, up_aux, weff);
        int grid = (M / 64) * (N / 64);
        gemm_f32_fallback<<<grid, 256, 0, stream>>>(hs, weff, b, out, M, N, K);
    }
}

// Round 14
// 241.499 us; speedup vs baseline: 1.3486x; 1.3486x over previous
//
#include <hip/hip_runtime.h>
#include <hip/hip_bf16.h>
#include <stdint.h>

#define ALPHA 1.0f

typedef __attribute__((ext_vector_type(8))) short bf16x8;
typedef __attribute__((ext_vector_type(4))) float f32x4;
typedef unsigned short ushort_t;

__device__ __forceinline__ unsigned short f32_to_bf16_rne(float f) {
    union { float f; unsigned int u; } v; v.f = f;
    unsigned int u = v.u;
    unsigned int r = u + 0x7FFFu + ((u >> 16) & 1u);
    return (unsigned short)(r >> 16);
}

__device__ __forceinline__ unsigned int cvt_pk_bf16(float lo, float hi) {
    unsigned int r;
    asm("v_cvt_pk_bf16_f32 %0, %1, %2" : "=v"(r) : "v"(lo), "v"(hi));
    return r;
}

__device__ __forceinline__ void async_copy16(const void* g, void* l) {
    __builtin_amdgcn_global_load_lds(
        (const __attribute__((address_space(1))) void*)g,
        (__attribute__((address_space(3))) void*)l, 16, 0, 0);
}

// ---------------------------------------------------------------------------
// Fused W_eff: weff[o][i] = W[o][i] + ALPHA * sum_r fac[o][r] * t1[r][i]
template <bool BF16OUT>
__global__ __launch_bounds__(256)
void weff_fused_kernel(const float* __restrict__ W,
                       const float* __restrict__ lora_down,
                       const float* __restrict__ lora_up,
                       const float* __restrict__ down_aux,
                       const float* __restrict__ up_aux,
                       void* __restrict__ weff) {
    int o = blockIdx.x;
    int i0 = threadIdx.x * 4;

    float fac[4] = {0.f, 0.f, 0.f, 0.f};
    for (int u = 0; u < 50; ++u) {
        float ua = up_aux[o * 50 + u] * ALPHA;
#pragma unroll
        for (int r = 0; r < 4; ++r) fac[r] += ua * lora_up[u * 4 + r];
    }

    float4 t1[4];
#pragma unroll
    for (int r = 0; r < 4; ++r) t1[r] = make_float4(0.f, 0.f, 0.f, 0.f);
    for (int d = 0; d < 100; ++d) {
        float4 da = *(const float4*)(down_aux + d * 1024 + i0);
#pragma unroll
        for (int r = 0; r < 4; ++r) {
            float ld = lora_down[r * 100 + d];
            t1[r].x += ld * da.x; t1[r].y += ld * da.y;
            t1[r].z += ld * da.z; t1[r].w += ld * da.w;
        }
    }

    float4 acc = *(const float4*)(W + (long)o * 1024 + i0);
#pragma unroll
    for (int r = 0; r < 4; ++r) {
        acc.x += fac[r] * t1[r].x; acc.y += fac[r] * t1[r].y;
        acc.z += fac[r] * t1[r].z; acc.w += fac[r] * t1[r].w;
    }

    if (BF16OUT) {
        ushort4 rr;
        rr.x = f32_to_bf16_rne(acc.x); rr.y = f32_to_bf16_rne(acc.y);
        rr.z = f32_to_bf16_rne(acc.z); rr.w = f32_to_bf16_rne(acc.w);
        *(ushort4*)((ushort_t*)weff + (long)o * 1024 + i0) = rr;
    } else {
        *(float4*)((float*)weff + (long)o * 1024 + i0) = acc;
    }
}

// ---------------------------------------------------------------------------
// Fully-fused GEMM: C = cvt_bf16(A_f32[M][K]) * Bt_bf16[N][K]^T + bias
// 256x256x64 tile, 8 waves (2Mx4N), per-wave 128x64 = acc[8][4] f32x4.
// R7's 2-barrier counted-vmcnt skeleton (measured 188us) + fused A cvt with
// FULL-ITERATION load age (fixes R8's per-iter ~500cyc stall):
//
// Per iter j (buf c=j&1, o=c^1), FIFO queue audit (steady state):
//   [B0]  queue = [A(j+1) 8, B(j+1) 4]
//   1. writeAh0/h1: cvt vP/vQ (A(j+1), loaded at iter j-1) -> Ab[o]
//      compiler waits vmcnt(8) / vmcnt(4): aged 1 full iter -> NO stall
//   2. loadA(j+2) -> vP/vQ (regs freed by step 1); queue [B(j+1)4, A(j+2)8]
//   3. frag reads aL,bL -> Q0 -> bH -> Q1 -> aH -> Q2  (buf c)
//   B2 (all buf-c LDS reads consumed pre-Q2)
//   4. stageB(j+2) -> Bb[c]; queue [B(j+1)4, A(j+2)8, B(j+2)4]
//   5. Q3 (pure regs, overlaps glds flight)
//   gate: vmcnt(12) retires B(j+1) (aged 1+ iter); lgkmcnt(0); [B0]
// Never a vmcnt(0) drain in the loop; every wait is full-iteration aged.
#define BMM 256
#define BNN 256
#define BKK 64

__global__ __launch_bounds__(512, 2)
void gemm_fused_kernel(const float* __restrict__ A,
                       const ushort_t* __restrict__ Bt,
                       const float* __restrict__ bias,
                       float* __restrict__ C, int M, int N, int K) {
    __shared__ __align__(16) ushort_t Ab[2][BMM * BKK];  // 2 x 32 KB
    __shared__ __align__(16) ushort_t Bb[2][BNN * BKK];  // 2 x 32 KB

    int nTilesN = N / BNN;  // 4
    int nwg = gridDim.x;
    int bid = blockIdx.x;
    int swz = bid;
    if ((nwg & 7) == 0) {   // grid = 1024 -> bijective XCD swizzle
        int cpx = nwg >> 3;
        swz = (bid & 7) * cpx + (bid >> 3);
    }
    int tm = swz / nTilesN;
    int tn = swz % nTilesN;
    const long rowA0 = (long)tm * BMM;
    const long colB0 = (long)tn * BNN;

    int tid = threadIdx.x;
    int lane = tid & 63;
    int wave = tid >> 6;     // 0..7
    int wr = wave >> 2;      // 0..1  (M)
    int wc = wave & 3;       // 0..3  (N)

    // ---- A staging map (per half-tile: 128 rows x 64 k f32) ----
    int amrow[2], amcol[2], amlds[2];
#pragma unroll
    for (int q = 0; q < 2; ++q) {
        int p = q * 512 + tid;
        amrow[q] = p >> 3;
        amcol[q] = p & 7;
        amlds[q] = amcol[q] ^ (amrow[q] & 7);
    }

    // ---- B staging map (glds, pre-swizzled source) ----
    int prow[2], pcg[2];
#pragma unroll
    for (int q = 0; q < 2; ++q) {
        int pc = q * 512 + tid;
        prow[q] = pc >> 3;
        pcg[q] = (pc & 7) ^ (prow[q] & 7);
    }

    // fragment map
    int fr = lane & 15;
    int h4 = lane >> 4;
    int s7 = fr & 7;
    int aoff = (wr * 128 + fr) * 64;
    int boff = (wc * 64 + fr) * 64;
    int ck[2] = { (h4 ^ s7) * 8, ((4 + h4) ^ s7) * 8 };

    f32x4 acc[8][4];
#pragma unroll
    for (int m = 0; m < 8; ++m)
#pragma unroll
        for (int n = 0; n < 4; ++n) acc[m][n] = (f32x4)(0.0f);

    const int nIter = K / BKK;  // 16

    // A staging regs: vP = half0, vQ = half1 (32 VGPR)
    float4 vP0[2], vP1[2], vQ0[2], vQ1[2];

    auto loadAh0 = [&](int kt) {
        const float* src = A + rowA0 * (long)K + kt * BKK;
#pragma unroll
        for (int q = 0; q < 2; ++q) {
            const float* gp = src + (long)amrow[q] * K + amcol[q] * 8;
            vP0[q] = ((const float4*)gp)[0];
            vP1[q] = ((const float4*)gp)[1];
        }
    };
    auto loadAh1 = [&](int kt) {
        const float* src = A + (rowA0 + 128) * (long)K + kt * BKK;
#pragma unroll
        for (int q = 0; q < 2; ++q) {
            const float* gp = src + (long)amrow[q] * K + amcol[q] * 8;
            vQ0[q] = ((const float4*)gp)[0];
            vQ1[q] = ((const float4*)gp)[1];
        }
    };
    auto writeAh0 = [&](int bufsel) {
        ushort_t* dst = &Ab[bufsel][0];
#pragma unroll
        for (int q = 0; q < 2; ++q) {
            uint4 w;
            w.x = cvt_pk_bf16(vP0[q].x, vP0[q].y);
            w.y = cvt_pk_bf16(vP0[q].z, vP0[q].w);
            w.z = cvt_pk_bf16(vP1[q].x, vP1[q].y);
            w.w = cvt_pk_bf16(vP1[q].z, vP1[q].w);
            *(uint4*)(dst + amrow[q] * 64 + amlds[q] * 8) = w;
        }
    };
    auto writeAh1 = [&](int bufsel) {
        ushort_t* dst = &Ab[bufsel][8192];
#pragma unroll
        for (int q = 0; q < 2; ++q) {
            uint4 w;
            w.x = cvt_pk_bf16(vQ0[q].x, vQ0[q].y);
            w.y = cvt_pk_bf16(vQ0[q].z, vQ0[q].w);
            w.z = cvt_pk_bf16(vQ1[q].x, vQ1[q].y);
            w.w = cvt_pk_bf16(vQ1[q].z, vQ1[q].w);
            *(uint4*)(dst + amrow[q] * 64 + amlds[q] * 8) = w;
        }
    };
    auto stageB = [&](int kt, int h, int bufsel) {
        const ushort_t* src = Bt + (colB0 + h * 128) * (long)K + kt * BKK;
        ushort_t* dst = &Bb[bufsel][h * 8192 + wave * 512];
#pragma unroll
        for (int q = 0; q < 2; ++q)
            async_copy16(src + (long)prow[q] * K + pcg[q] * 8, dst + q * 4096);
    };

    // ---------------- prologue (builds steady queue [A1 8, B1 4]) ----------
    loadAh0(0); loadAh1(0);               // [A0 8]
    stageB(0, 0, 0); stageB(0, 1, 0);     // [A0 8, B0 4]
    writeAh0(0); writeAh1(0);             // waits vmcnt(8)/(4): one-time HBM
    loadAh0(1); loadAh1(1);               // [B0 4, A1 8]
    stageB(1, 0, 1); stageB(1, 1, 1);     // [B0 4, A1 8, B1 4]
    asm volatile("s_waitcnt vmcnt(12) lgkmcnt(0)" ::: "memory");  // B0 landed
    __builtin_amdgcn_s_barrier();

#pragma unroll 1
    for (int j = 0; j < nIter; ++j) {
        int c = j & 1, o = c ^ 1;
        const ushort_t* Ac = &Ab[c][0];
        const ushort_t* Bc = &Bb[c][0];
        bool s1 = (j + 1 < nIter);
        bool s2 = (j + 2 < nIter);

        // 1. cvt+write A(j+1) -> Ab[o]  (full-iter-aged loads; counted waits)
        if (s1) { writeAh0(o); writeAh1(o); }
        // 2. reload vP/vQ with A(j+2)
        if (s2) { loadAh0(j + 2); loadAh1(j + 2); }

        // 3. fragment reads + quadrants (buf c)
        bf16x8 aL[4][2], aH[4][2], bL[2][2], bH[2][2];
#pragma unroll
        for (int m = 0; m < 4; ++m)
#pragma unroll
            for (int kk = 0; kk < 2; ++kk)
                aL[m][kk] = *(const bf16x8*)&Ac[aoff + m * 1024 + ck[kk]];
#pragma unroll
        for (int n = 0; n < 2; ++n)
#pragma unroll
            for (int kk = 0; kk < 2; ++kk)
                bL[n][kk] = *(const bf16x8*)&Bc[boff + n * 1024 + ck[kk]];

        // Q0: aL x bL
        __builtin_amdgcn_s_setprio(1);
#pragma unroll
        for (int m = 0; m < 4; ++m)
#pragma unroll
            for (int n = 0; n < 2; ++n)
#pragma unroll
                for (int kk = 0; kk < 2; ++kk)
                    acc[m][n] = __builtin_amdgcn_mfma_f32_16x16x32_bf16(
                        aL[m][kk], bL[n][kk], acc[m][n], 0, 0, 0);
        __builtin_amdgcn_s_setprio(0);

        // bH reads
#pragma unroll
        for (int n = 0; n < 2; ++n)
#pragma unroll
            for (int kk = 0; kk < 2; ++kk)
                bH[n][kk] = *(const bf16x8*)&Bc[boff + (n + 2) * 1024 + ck[kk]];

        // Q1: aL x bH
        __builtin_amdgcn_s_setprio(1);
#pragma unroll
        for (int m = 0; m < 4; ++m)
#pragma unroll
            for (int n = 0; n < 2; ++n)
#pragma unroll
                for (int kk = 0; kk < 2; ++kk)
                    acc[m][n + 2] = __builtin_amdgcn_mfma_f32_16x16x32_bf16(
                        aL[m][kk], bH[n][kk], acc[m][n + 2], 0, 0, 0);
        __builtin_amdgcn_s_setprio(0);

        // aH reads
#pragma unroll
        for (int m = 0; m < 4; ++m)
#pragma unroll
            for (int kk = 0; kk < 2; ++kk)
                aH[m][kk] = *(const bf16x8*)&Ac[aoff + (m + 4) * 1024 + ck[kk]];

        // Q2: aH x bH
        __builtin_amdgcn_s_setprio(1);
#pragma unroll
        for (int m = 0; m < 4; ++m)
#pragma unroll
            for (int n = 0; n < 2; ++n)
#pragma unroll
                for (int kk = 0; kk < 2; ++kk)
                    acc[m + 4][n + 2] = __builtin_amdgcn_mfma_f32_16x16x32_bf16(
                        aH[m][kk], bH[n][kk], acc[m + 4][n + 2], 0, 0, 0);
        __builtin_amdgcn_s_setprio(0);

        // all buf-c LDS reads consumed -> safe to restage Bb[c]
        __builtin_amdgcn_s_barrier();            // B2

        // 4. stage B(j+2) -> Bb[c]
        if (s2) { stageB(j + 2, 0, c); stageB(j + 2, 1, c); }

        // 5. Q3: aH x bL (pure regs; overlaps glds flight)
        __builtin_amdgcn_s_setprio(1);
#pragma unroll
        for (int m = 0; m < 4; ++m)
#pragma unroll
            for (int n = 0; n < 2; ++n)
#pragma unroll
                for (int kk = 0; kk < 2; ++kk)
                    acc[m + 4][n] = __builtin_amdgcn_mfma_f32_16x16x32_bf16(
                        aH[m][kk], bL[n][kk], acc[m + 4][n], 0, 0, 0);
        __builtin_amdgcn_s_setprio(0);

        // gate: retire B(j+1) (aged 1+ iter); keep A(j+2)+B(j+2) in flight
        if (s2) {
            asm volatile("s_waitcnt vmcnt(12) lgkmcnt(0)" ::: "memory");
        } else {
            asm volatile("s_waitcnt vmcnt(0) lgkmcnt(0)" ::: "memory");
        }
        __builtin_amdgcn_s_barrier();            // B0
    }

    // ---- epilogue: C = acc + bias ----
    int ccol = lane & 15;
    int crow = (lane >> 4) * 4;
#pragma unroll
    for (int m = 0; m < 8; ++m) {
        long grow = rowA0 + wr * 128 + m * 16 + crow;
#pragma unroll
        for (int n = 0; n < 4; ++n) {
            long gcol = colB0 + wc * 64 + n * 16 + ccol;
            float bb = bias[gcol];
#pragma unroll
            for (int r = 0; r < 4; ++r) {
                C[(grow + r) * N + gcol] = acc[m][n][r] + bb;
            }
        }
    }
}

// ---------------------------------------------------------------------------
// Fallback: plain f32 tiled GEMM (used only if ws too small for bf16 path)
__global__ __launch_bounds__(256)
void gemm_f32_fallback(const float* __restrict__ A, const float* __restrict__ Bt,
                       const float* __restrict__ bias, float* __restrict__ C,
                       int M, int N, int K) {
    __shared__ float As[64][17];
    __shared__ float Bs[64][17];
    int tilesN = N / 64;
    int tm = blockIdx.x / tilesN;
    int tn = blockIdx.x % tilesN;
    int tid = threadIdx.x;
    int tr = tid / 16, tc = tid % 16;
    float acc[4][4] = {};
    for (int k0 = 0; k0 < K; k0 += 16) {
        for (int t = tid; t < 64 * 16; t += 256) {
            int r = t / 16, c = t % 16;
            As[r][c] = A[((long)tm * 64 + r) * K + k0 + c];
            Bs[r][c] = Bt[((long)tn * 64 + r) * K + k0 + c];
        }
        __syncthreads();
#pragma unroll
        for (int kk = 0; kk < 16; ++kk) {
            float av[4], bv[4];
#pragma unroll
            for (int i = 0; i < 4; ++i) av[i] = As[tr * 4 + i][kk];
#pragma unroll
            for (int j = 0; j < 4; ++j) bv[j] = Bs[tc * 4 + j][kk];
#pragma unroll
            for (int i = 0; i < 4; ++i)
#pragma unroll
                for (int j = 0; j < 4; ++j) acc[i][j] += av[i] * bv[j];
        }
        __syncthreads();
    }
#pragma unroll
    for (int i = 0; i < 4; ++i) {
        long row = (long)tm * 64 + tr * 4 + i;
#pragma unroll
        for (int j = 0; j < 4; ++j) {
            long col = (long)tn * 64 + tc * 4 + j;
            C[row * N + col] = acc[i][j] + bias[col];
        }
    }
}

// ---------------------------------------------------------------------------
extern "C" void kernel_launch(void* const* d_in, const int* in_sizes, int n_in,
                              void* d_out, int out_size, void* d_ws, size_t ws_size,
                              hipStream_t stream) {
    const float* hs        = (const float*)d_in[0];
    const float* W         = (const float*)d_in[1];
    const float* b         = (const float*)d_in[2];
    const float* lora_down = (const float*)d_in[3];
    const float* lora_up   = (const float*)d_in[4];
    const float* down_aux  = (const float*)d_in[5];
    const float* up_aux    = (const float*)d_in[6];
    float* out = (float*)d_out;

    const int K = 1024;   // IN
    const int N = 1024;   // OUT
    const int M = in_sizes[0] / K;  // B*S = 65536

    char* ws = (char*)d_ws;
    const size_t NEED_FAST = 2 * 1024 * 1024;   // weff bf16 only

    if (ws_size >= NEED_FAST && (M % BMM) == 0) {
        ushort_t* weff = (ushort_t*)ws;
        weff_fused_kernel<true><<<N, 256, 0, stream>>>(W, lora_down, lora_up,
                                                       down_aux, up_aux, weff);
        int grid = (M / BMM) * (N / BNN);   // 1024
        gemm_fused_kernel<<<grid, 512, 0, stream>>>(hs, weff, b, out, M, N, K);
    } else {
        float* weff = (float*)ws;  // 4MB
        weff_fused_kernel<false><<<N, 256, 0, stream>>>(W, lora_down, lora_up,
                                                        down_aux, up_aux, weff);
        int grid = (M / 64) * (N / 64);
        gemm_f32_fallback<<<grid, 256, 0, stream>>>(hs, weff, b, out, M, N, K);
    }
}

// Round 15
// 233.892 us; speedup vs baseline: 1.3925x; 1.0325x over previous
//
#include <hip/hip_runtime.h>
#include <hip/hip_bf16.h>
#include <stdint.h>

#define ALPHA 1.0f

typedef __attribute__((ext_vector_type(8))) short bf16x8;
typedef __attribute__((ext_vector_type(4))) float f32x4;
typedef unsigned short ushort_t;

__device__ __forceinline__ unsigned short f32_to_bf16_rne(float f) {
    union { float f; unsigned int u; } v; v.f = f;
    unsigned int u = v.u;
    unsigned int r = u + 0x7FFFu + ((u >> 16) & 1u);
    return (unsigned short)(r >> 16);
}

__device__ __forceinline__ unsigned int cvt_pk_bf16(float lo, float hi) {
    unsigned int r;
    asm("v_cvt_pk_bf16_f32 %0, %1, %2" : "=v"(r) : "v"(lo), "v"(hi));
    return r;
}

__device__ __forceinline__ void async_copy16(const void* g, void* l) {
    __builtin_amdgcn_global_load_lds(
        (const __attribute__((address_space(1))) void*)g,
        (__attribute__((address_space(3))) void*)l, 16, 0, 0);
}

// ---------------------------------------------------------------------------
// Fused W_eff: weff[o][i] = W[o][i] + ALPHA * sum_r fac[o][r] * t1[r][i]
template <bool BF16OUT>
__global__ __launch_bounds__(256)
void weff_fused_kernel(const float* __restrict__ W,
                       const float* __restrict__ lora_down,
                       const float* __restrict__ lora_up,
                       const float* __restrict__ down_aux,
                       const float* __restrict__ up_aux,
                       void* __restrict__ weff) {
    int o = blockIdx.x;
    int i0 = threadIdx.x * 4;

    float fac[4] = {0.f, 0.f, 0.f, 0.f};
    for (int u = 0; u < 50; ++u) {
        float ua = up_aux[o * 50 + u] * ALPHA;
#pragma unroll
        for (int r = 0; r < 4; ++r) fac[r] += ua * lora_up[u * 4 + r];
    }

    float4 t1[4];
#pragma unroll
    for (int r = 0; r < 4; ++r) t1[r] = make_float4(0.f, 0.f, 0.f, 0.f);
    for (int d = 0; d < 100; ++d) {
        float4 da = *(const float4*)(down_aux + d * 1024 + i0);
#pragma unroll
        for (int r = 0; r < 4; ++r) {
            float ld = lora_down[r * 100 + d];
            t1[r].x += ld * da.x; t1[r].y += ld * da.y;
            t1[r].z += ld * da.z; t1[r].w += ld * da.w;
        }
    }

    float4 acc = *(const float4*)(W + (long)o * 1024 + i0);
#pragma unroll
    for (int r = 0; r < 4; ++r) {
        acc.x += fac[r] * t1[r].x; acc.y += fac[r] * t1[r].y;
        acc.z += fac[r] * t1[r].z; acc.w += fac[r] * t1[r].w;
    }

    if (BF16OUT) {
        ushort4 rr;
        rr.x = f32_to_bf16_rne(acc.x); rr.y = f32_to_bf16_rne(acc.y);
        rr.z = f32_to_bf16_rne(acc.z); rr.w = f32_to_bf16_rne(acc.w);
        *(ushort4*)((ushort_t*)weff + (long)o * 1024 + i0) = rr;
    } else {
        *(float4*)((float*)weff + (long)o * 1024 + i0) = acc;
    }
}

// ---------------------------------------------------------------------------
// Fully-fused GEMM: C = cvt_bf16(A_f32[M][K]) * Bt_bf16[N][K]^T + bias
// 256x256x64 tile, 8 waves (2Mx4N), per-wave 128x64 = acc[8][4] f32x4.
// R7's 2-barrier counted-vmcnt skeleton + fused A cvt combining:
//   - R8's PLACEMENT: writeAh0 post-Q0, writeAh1 post-Q2 (cvt+ds_write run
//     in the MFMA shadow, not serially at iter head like R14);
//   - R14's LOAD AGE: vP/vQ loaded at iter j-1's B2 (full-iteration aged,
//     so writeAh0's vmcnt(8) / writeAh1's vmcnt(4) never stall like R8).
//
// FIFO queue audit, steady state (iter j, buf c=j&1, o=c^1):
//   [B0] queue = [A(j+1) 8, B(j+1) 4]
//   aL,bL reads; Q0
//   writeAh0(o): waits vmcnt(8) (A(j+1)h0, aged 1 iter) -> no stall
//   bH reads; Q1; aH reads; Q2
//   writeAh1(o): waits vmcnt(4) (A(j+1)h1, aged 1 iter) -> no stall
//   B2 (all buf-c LDS reads retired chip-wide)
//   stageB(j+2)->Bb[c]; loadA(j+2)->vP/vQ (regs freed by the writes)
//   Q3 (pure regs, overlaps 12 in-flight VMEM)
//   gate: vmcnt(12) lgkmcnt(0)  (retires B(j+1), aged 1 iter); [B0]
// No stall-able wait anywhere in the steady-state loop.
#define BMM 256
#define BNN 256
#define BKK 64

__global__ __launch_bounds__(512, 2)
void gemm_fused_kernel(const float* __restrict__ A,
                       const ushort_t* __restrict__ Bt,
                       const float* __restrict__ bias,
                       float* __restrict__ C, int M, int N, int K) {
    __shared__ __align__(16) ushort_t Ab[2][BMM * BKK];  // 2 x 32 KB
    __shared__ __align__(16) ushort_t Bb[2][BNN * BKK];  // 2 x 32 KB

    int nTilesN = N / BNN;  // 4
    int nwg = gridDim.x;
    int bid = blockIdx.x;
    int swz = bid;
    if ((nwg & 7) == 0) {   // grid = 1024 -> bijective XCD swizzle
        int cpx = nwg >> 3;
        swz = (bid & 7) * cpx + (bid >> 3);
    }
    int tm = swz / nTilesN;
    int tn = swz % nTilesN;
    const long rowA0 = (long)tm * BMM;
    const long colB0 = (long)tn * BNN;

    int tid = threadIdx.x;
    int lane = tid & 63;
    int wave = tid >> 6;     // 0..7
    int wr = wave >> 2;      // 0..1  (M)
    int wc = wave & 3;       // 0..3  (N)

    // ---- A staging map (per half-tile: 128 rows x 64 k f32) ----
    int amrow[2], amcol[2], amlds[2];
#pragma unroll
    for (int q = 0; q < 2; ++q) {
        int p = q * 512 + tid;
        amrow[q] = p >> 3;
        amcol[q] = p & 7;
        amlds[q] = amcol[q] ^ (amrow[q] & 7);
    }

    // ---- B staging map (glds, pre-swizzled source) ----
    int prow[2], pcg[2];
#pragma unroll
    for (int q = 0; q < 2; ++q) {
        int pc = q * 512 + tid;
        prow[q] = pc >> 3;
        pcg[q] = (pc & 7) ^ (prow[q] & 7);
    }

    // fragment map
    int fr = lane & 15;
    int h4 = lane >> 4;
    int s7 = fr & 7;
    int aoff = (wr * 128 + fr) * 64;
    int boff = (wc * 64 + fr) * 64;
    int ck[2] = { (h4 ^ s7) * 8, ((4 + h4) ^ s7) * 8 };

    f32x4 acc[8][4];
#pragma unroll
    for (int m = 0; m < 8; ++m)
#pragma unroll
        for (int n = 0; n < 4; ++n) acc[m][n] = (f32x4)(0.0f);

    const int nIter = K / BKK;  // 16

    // A staging regs: vP = half0, vQ = half1 (32 VGPR)
    float4 vP0[2], vP1[2], vQ0[2], vQ1[2];

    auto loadAh0 = [&](int kt) {
        const float* src = A + rowA0 * (long)K + kt * BKK;
#pragma unroll
        for (int q = 0; q < 2; ++q) {
            const float* gp = src + (long)amrow[q] * K + amcol[q] * 8;
            vP0[q] = ((const float4*)gp)[0];
            vP1[q] = ((const float4*)gp)[1];
        }
    };
    auto loadAh1 = [&](int kt) {
        const float* src = A + (rowA0 + 128) * (long)K + kt * BKK;
#pragma unroll
        for (int q = 0; q < 2; ++q) {
            const float* gp = src + (long)amrow[q] * K + amcol[q] * 8;
            vQ0[q] = ((const float4*)gp)[0];
            vQ1[q] = ((const float4*)gp)[1];
        }
    };
    auto writeAh0 = [&](int bufsel) {
        ushort_t* dst = &Ab[bufsel][0];
#pragma unroll
        for (int q = 0; q < 2; ++q) {
            uint4 w;
            w.x = cvt_pk_bf16(vP0[q].x, vP0[q].y);
            w.y = cvt_pk_bf16(vP0[q].z, vP0[q].w);
            w.z = cvt_pk_bf16(vP1[q].x, vP1[q].y);
            w.w = cvt_pk_bf16(vP1[q].z, vP1[q].w);
            *(uint4*)(dst + amrow[q] * 64 + amlds[q] * 8) = w;
        }
    };
    auto writeAh1 = [&](int bufsel) {
        ushort_t* dst = &Ab[bufsel][8192];
#pragma unroll
        for (int q = 0; q < 2; ++q) {
            uint4 w;
            w.x = cvt_pk_bf16(vQ0[q].x, vQ0[q].y);
            w.y = cvt_pk_bf16(vQ0[q].z, vQ0[q].w);
            w.z = cvt_pk_bf16(vQ1[q].x, vQ1[q].y);
            w.w = cvt_pk_bf16(vQ1[q].z, vQ1[q].w);
            *(uint4*)(dst + amrow[q] * 64 + amlds[q] * 8) = w;
        }
    };
    auto stageB = [&](int kt, int h, int bufsel) {
        const ushort_t* src = Bt + (colB0 + h * 128) * (long)K + kt * BKK;
        ushort_t* dst = &Bb[bufsel][h * 8192 + wave * 512];
#pragma unroll
        for (int q = 0; q < 2; ++q)
            async_copy16(src + (long)prow[q] * K + pcg[q] * 8, dst + q * 4096);
    };

    // ---------------- prologue (builds steady queue [A1 8, B1 4]) ----------
    loadAh0(0); loadAh1(0);               // [A0 8]
    stageB(0, 0, 0); stageB(0, 1, 0);     // [A0 8, B0 4]
    writeAh0(0); writeAh1(0);             // waits vmcnt(8)/(4): one-time HBM
    loadAh0(1); loadAh1(1);               // [B0 4, A1 8]
    stageB(1, 0, 1); stageB(1, 1, 1);     // [B0 4, A1 8, B1 4]
    asm volatile("s_waitcnt vmcnt(12) lgkmcnt(0)" ::: "memory");  // B0 landed
    __builtin_amdgcn_s_barrier();

#pragma unroll 1
    for (int j = 0; j < nIter; ++j) {
        int c = j & 1, o = c ^ 1;
        const ushort_t* Ac = &Ab[c][0];
        const ushort_t* Bc = &Bb[c][0];
        bool s1 = (j + 1 < nIter);
        bool s2 = (j + 2 < nIter);

        // ---- aL, bL fragment reads (buf c) ----
        bf16x8 aL[4][2], aH[4][2], bL[2][2], bH[2][2];
#pragma unroll
        for (int m = 0; m < 4; ++m)
#pragma unroll
            for (int kk = 0; kk < 2; ++kk)
                aL[m][kk] = *(const bf16x8*)&Ac[aoff + m * 1024 + ck[kk]];
#pragma unroll
        for (int n = 0; n < 2; ++n)
#pragma unroll
            for (int kk = 0; kk < 2; ++kk)
                bL[n][kk] = *(const bf16x8*)&Bc[boff + n * 1024 + ck[kk]];

        // Q0: aL x bL
        __builtin_amdgcn_s_setprio(1);
#pragma unroll
        for (int m = 0; m < 4; ++m)
#pragma unroll
            for (int n = 0; n < 2; ++n)
#pragma unroll
                for (int kk = 0; kk < 2; ++kk)
                    acc[m][n] = __builtin_amdgcn_mfma_f32_16x16x32_bf16(
                        aL[m][kk], bL[n][kk], acc[m][n], 0, 0, 0);
        __builtin_amdgcn_s_setprio(0);

        // cvt+write A(j+1)h0 -> Ab[o]  (vP aged 1 iter: vmcnt(8) satisfied)
        if (s1) writeAh0(o);

        // bH reads
#pragma unroll
        for (int n = 0; n < 2; ++n)
#pragma unroll
            for (int kk = 0; kk < 2; ++kk)
                bH[n][kk] = *(const bf16x8*)&Bc[boff + (n + 2) * 1024 + ck[kk]];

        // Q1: aL x bH
        __builtin_amdgcn_s_setprio(1);
#pragma unroll
        for (int m = 0; m < 4; ++m)
#pragma unroll
            for (int n = 0; n < 2; ++n)
#pragma unroll
                for (int kk = 0; kk < 2; ++kk)
                    acc[m][n + 2] = __builtin_amdgcn_mfma_f32_16x16x32_bf16(
                        aL[m][kk], bH[n][kk], acc[m][n + 2], 0, 0, 0);
        __builtin_amdgcn_s_setprio(0);

        // aH reads
#pragma unroll
        for (int m = 0; m < 4; ++m)
#pragma unroll
            for (int kk = 0; kk < 2; ++kk)
                aH[m][kk] = *(const bf16x8*)&Ac[aoff + (m + 4) * 1024 + ck[kk]];

        // Q2: aH x bH
        __builtin_amdgcn_s_setprio(1);
#pragma unroll
        for (int m = 0; m < 4; ++m)
#pragma unroll
            for (int n = 0; n < 2; ++n)
#pragma unroll
                for (int kk = 0; kk < 2; ++kk)
                    acc[m + 4][n + 2] = __builtin_amdgcn_mfma_f32_16x16x32_bf16(
                        aH[m][kk], bH[n][kk], acc[m + 4][n + 2], 0, 0, 0);
        __builtin_amdgcn_s_setprio(0);

        // cvt+write A(j+1)h1 -> Ab[o]  (vQ aged 1 iter: vmcnt(4) satisfied)
        if (s1) writeAh1(o);

        // all buf-c LDS reads consumed -> safe to restage Bb[c]
        __builtin_amdgcn_s_barrier();            // B2

        // stage B(j+2) -> Bb[c]; reload vP/vQ with A(j+2)
        if (s2) {
            stageB(j + 2, 0, c); stageB(j + 2, 1, c);
            loadAh0(j + 2); loadAh1(j + 2);
        }

        // Q3: aH x bL (pure regs; overlaps the in-flight VMEM)
        __builtin_amdgcn_s_setprio(1);
#pragma unroll
        for (int m = 0; m < 4; ++m)
#pragma unroll
            for (int n = 0; n < 2; ++n)
#pragma unroll
                for (int kk = 0; kk < 2; ++kk)
                    acc[m + 4][n] = __builtin_amdgcn_mfma_f32_16x16x32_bf16(
                        aH[m][kk], bL[n][kk], acc[m + 4][n], 0, 0, 0);
        __builtin_amdgcn_s_setprio(0);

        // gate: retire B(j+1) (aged 1 iter); keep A(j+2)+B(j+2) in flight
        if (s2) {
            asm volatile("s_waitcnt vmcnt(12) lgkmcnt(0)" ::: "memory");
        } else {
            asm volatile("s_waitcnt vmcnt(0) lgkmcnt(0)" ::: "memory");
        }
        __builtin_amdgcn_s_barrier();            // B0
    }

    // ---- epilogue: C = acc + bias ----
    int ccol = lane & 15;
    int crow = (lane >> 4) * 4;
#pragma unroll
    for (int m = 0; m < 8; ++m) {
        long grow = rowA0 + wr * 128 + m * 16 + crow;
#pragma unroll
        for (int n = 0; n < 4; ++n) {
            long gcol = colB0 + wc * 64 + n * 16 + ccol;
            float bb = bias[gcol];
#pragma unroll
            for (int r = 0; r < 4; ++r) {
                C[(grow + r) * N + gcol] = acc[m][n][r] + bb;
            }
        }
    }
}

// ---------------------------------------------------------------------------
// Fallback: plain f32 tiled GEMM (used only if ws too small for bf16 path)
__global__ __launch_bounds__(256)
void gemm_f32_fallback(const float* __restrict__ A, const float* __restrict__ Bt,
                       const float* __restrict__ bias, float* __restrict__ C,
                       int M, int N, int K) {
    __shared__ float As[64][17];
    __shared__ float Bs[64][17];
    int tilesN = N / 64;
    int tm = blockIdx.x / tilesN;
    int tn = blockIdx.x % tilesN;
    int tid = threadIdx.x;
    int tr = tid / 16, tc = tid % 16;
    float acc[4][4] = {};
    for (int k0 = 0; k0 < K; k0 += 16) {
        for (int t = tid; t < 64 * 16; t += 256) {
            int r = t / 16, c = t % 16;
            As[r][c] = A[((long)tm * 64 + r) * K + k0 + c];
            Bs[r][c] = Bt[((long)tn * 64 + r) * K + k0 + c];
        }
        __syncthreads();
#pragma unroll
        for (int kk = 0; kk < 16; ++kk) {
            float av[4], bv[4];
#pragma unroll
            for (int i = 0; i < 4; ++i) av[i] = As[tr * 4 + i][kk];
#pragma unroll
            for (int j = 0; j < 4; ++j) bv[j] = Bs[tc * 4 + j][kk];
#pragma unroll
            for (int i = 0; i < 4; ++i)
#pragma unroll
                for (int j = 0; j < 4; ++j) acc[i][j] += av[i] * bv[j];
        }
        __syncthreads();
    }
#pragma unroll
    for (int i = 0; i < 4; ++i) {
        long row = (long)tm * 64 + tr * 4 + i;
#pragma unroll
        for (int j = 0; j < 4; ++j) {
            long col = (long)tn * 64 + tc * 4 + j;
            C[row * N + col] = acc[i][j] + bias[col];
        }
    }
}

// ---------------------------------------------------------------------------
extern "C" void kernel_launch(void* const* d_in, const int* in_sizes, int n_in,
                              void* d_out, int out_size, void* d_ws, size_t ws_size,
                              hipStream_t stream) {
    const float* hs        = (const float*)d_in[0];
    const float* W         = (const float*)d_in[1];
    const float* b         = (const float*)d_in[2];
    const float* lora_down = (const float*)d_in[3];
    const float* lora_up   = (const float*)d_in[4];
    const float* down_aux  = (const float*)d_in[5];
    const float* up_aux    = (const float*)d_in[6];
    float* out = (float*)d_out;

    const int K = 1024;   // IN
    const int N = 1024;   // OUT
    const int M = in_sizes[0] / K;  // B*S = 65536

    char* ws = (char*)d_ws;
    const size_t NEED_FAST = 2 * 1024 * 1024;   // weff bf16 only

    if (ws_size >= NEED_FAST && (M % BMM) == 0) {
        ushort_t* weff = (ushort_t*)ws;
        weff_fused_kernel<true><<<N, 256, 0, stream>>>(W, lora_down, lora_up,
                                                       down_aux, up_aux, weff);
        int grid = (M / BMM) * (N / BNN);   // 1024
        gemm_fused_kernel<<<grid, 512, 0, stream>>>(hs, weff, b, out, M, N, K);
    } else {
        float* weff = (float*)ws;  // 4MB
        weff_fused_kernel<false><<<N, 256, 0, stream>>>(W, lora_down, lora_up,
                                                        down_aux, up_aux, weff);
        int grid = (M / 64) * (N / 64);
        gemm_f32_fallback<<<grid, 256, 0, stream>>>(hs, weff, b, out, M, N, K);
    }
}